// Round 12
// baseline (608.689 us; speedup 1.0000x reference)
//
#include <hip/hip_runtime.h>
#include <hip/hip_bf16.h>
#include <stdint.h>

#define BB 8
#define LL 4096
#define DD 64
#define KT1 128              // k-columns per tile
#define NT1 (LL / KT1)       // 32 tiles

typedef short bf16x8 __attribute__((ext_vector_type(8)));
typedef short bf16x4 __attribute__((ext_vector_type(4)));
typedef float f32x4 __attribute__((ext_vector_type(4)));

// Q pre-scale: (1/8) * log2(e), folding softmax scale AND exp->exp2 conversion.
#define QSCALE 0.1803368801111204f

__device__ inline short f2bfs(float x) {
    __hip_bfloat16 h = __float2bfloat16(x);
    return __builtin_bit_cast(short, h);
}

__device__ inline bf16x8 pack8v(f32x4 a, f32x4 b) {
    bf16x8 r;
    r[0] = f2bfs(a[0]); r[1] = f2bfs(a[1]); r[2] = f2bfs(a[2]); r[3] = f2bfs(a[3]);
    r[4] = f2bfs(b[0]); r[5] = f2bfs(b[1]); r[6] = f2bfs(b[2]); r[7] = f2bfs(b[3]);
    return r;
}

__device__ inline int swzK(int r) { return (r & 3) | (((r >> 3) & 1) << 2); }
__device__ inline int swzV(int r) { return (r & 7) ^ ((r >> 3) & 7); }

// Raw barrier: flush own LDS ops, leave global loads in flight (no vmcnt drain).
__device__ inline void wg_barrier() {
    asm volatile("s_waitcnt lgkmcnt(0)" ::: "memory");
    __builtin_amdgcn_s_barrier();
    __builtin_amdgcn_sched_barrier(0);
}

__global__ void detect_mask_kernel(const uint32_t* __restrict__ w, uint32_t* __restrict__ flag) {
    __shared__ int nonbin;
    if (threadIdx.x == 0) nonbin = 0;
    __syncthreads();
    int bad = 0;
    for (int i = threadIdx.x; i < 4096; i += 256) bad |= (w[i] > 1u) ? 1 : 0;
    if (bad) atomicOr(&nonbin, 1);
    __syncthreads();
    if (threadIdx.x == 0) *flag = (uint32_t)(nonbin != 0);
}

// ===================== K1: flash (no attn write) =====================
// Block = 64 q-rows of one batch, 8 waves (rg=w&3 q-group, ch=w>>2 k-half of 128).
// Permuted-K QK: lane (lr,lg) ends with P[q=16rg+lr][k = ch*64 + s*32 + lg*8 + t],
// which IS the PV A-fragment -> P never leaves registers. Writes out + rinv.
__global__ __launch_bounds__(512, 4) void flash_kernel(
    const float* __restrict__ qg, const float* __restrict__ kg,
    const float* __restrict__ vg, const void* __restrict__ maskv,
    const uint32_t* __restrict__ flagp,
    float* __restrict__ outp, float* __restrict__ rinvw)
{
    __shared__ alignas(16) ushort Kt[2][KT1 * 64];   // bf16 K   [krow][d]  (32 KB)
    __shared__ alignas(16) ushort Vt[2][64 * KT1];   // bf16 V^T [d][k]    (32 KB)
    __shared__ float Rs[128];

    const int tid = (int)threadIdx.x;
    const int w   = tid >> 6, l = tid & 63;
    const int lr  = l & 15, lg = l >> 4;
    const int rg  = w & 3, ch = w >> 2;
    const int id  = (int)blockIdx.x;     // id = qt*8 + b
    const int b   = id & 7;
    const int q0  = (id >> 3) * 64;
    const bool mbyte = (*flagp != 0);

    const float* kb = kg + (size_t)b * LL * DD;
    const float* vb = vg + (size_t)b * LL * DD;
    const int qrow = q0 + 16 * rg + lr;
    const uint8_t* mrow8  = (const uint8_t*)maskv + (size_t)b * LL * LL + (size_t)qrow * LL + ch * 64 + lg * 8;
    const int*     mrow32 = (const int*)maskv     + (size_t)b * LL * LL + (size_t)qrow * LL + ch * 64 + lg * 8;

    bf16x8 qf0, qf1;
    {
        const float* qp = qg + (size_t)(b * LL + qrow) * DD + lg * 8;
        qf0 = pack8v(*(const f32x4*)(qp)      * QSCALE, *(const f32x4*)(qp + 4)  * QSCALE);
        qf1 = pack8v(*(const f32x4*)(qp + 32) * QSCALE, *(const f32x4*)(qp + 36) * QSCALE);
    }

    const int krow0 = tid >> 3, kc8 = tid & 7;   // K: rows krow0, krow0+64
    const int vk4 = tid >> 4, vd4 = tid & 15;    // V: rows vk4*4..+3, cols vd4*4..+3

    f32x4 kS[4]; f32x4 vS[4]; uint64_t mS0 = 0, mS1 = 0;
    auto issS = [&](int kt) {
        const int kbase = kt * KT1;
        const float* p = kb + (size_t)(kbase + krow0) * DD + kc8 * 8;
        kS[0] = *(const f32x4*)p;            kS[1] = *(const f32x4*)(p + 4);
        const float* p2 = p + (size_t)64 * DD;
        kS[2] = *(const f32x4*)p2;           kS[3] = *(const f32x4*)(p2 + 4);
        const float* pv = vb + (size_t)(kbase + vk4 * 4) * DD + vd4 * 4;
        #pragma unroll
        for (int it = 0; it < 4; ++it) vS[it] = *(const f32x4*)(pv + it * DD);
        if (mbyte) {
            mS0 = *(const uint64_t*)(mrow8 + kbase);
            mS1 = *(const uint64_t*)(mrow8 + kbase + 32);
        }
    };
    auto comS = [&](int buf) {
        *(bf16x8*)&Kt[buf][krow0 * 64 + ((kc8 ^ swzK(krow0)) << 3)] = pack8v(kS[0], kS[1]);
        const int r1 = krow0 + 64;
        *(bf16x8*)&Kt[buf][r1 * 64 + ((kc8 ^ swzK(r1)) << 3)] = pack8v(kS[2], kS[3]);
        const int k0v = vk4 * 4;
        #pragma unroll
        for (int e = 0; e < 4; ++e) {
            const int d = vd4 * 4 + e;
            bf16x4 t;
            t[0] = f2bfs(vS[0][e]); t[1] = f2bfs(vS[1][e]);
            t[2] = f2bfs(vS[2][e]); t[3] = f2bfs(vS[3][e]);
            *(bf16x4*)&Vt[buf][d * KT1 + (((k0v >> 3) ^ swzV(d)) << 3) + (k0v & 7)] = t;
        }
    };

    float rsum = 0.f;
    f32x4 oacc[4];
    #pragma unroll
    for (int g = 0; g < 4; ++g) { f32x4 z = {0.f, 0.f, 0.f, 0.f}; oacc[g] = z; }

    auto body = [&](int buf, uint64_t m0, uint64_t m1, int kt) {
        const int kbase = kt * KT1;
        bf16x8 pa0, pa1;
        #pragma unroll
        for (int n = 0; n < 4; ++n) {
            const int krow = ch * 64 + ((n & 2) << 4) + ((lr >> 2) << 3) + ((n & 1) << 2) + (lr & 3);
            bf16x8 k0 = *(const bf16x8*)&Kt[buf][krow * 64 + ((lg       ^ swzK(krow)) << 3)];
            bf16x8 k1 = *(const bf16x8*)&Kt[buf][krow * 64 + (((4 + lg) ^ swzK(krow)) << 3)];
            f32x4 c = {0.f, 0.f, 0.f, 0.f};
            c = __builtin_amdgcn_mfma_f32_16x16x32_bf16(k0, qf0, c, 0, 0, 0);
            c = __builtin_amdgcn_mfma_f32_16x16x32_bf16(k1, qf1, c, 0, 0, 0);
            int4 mi = {0, 0, 0, 0};
            if (!mbyte) mi = *(const int4*)(mrow32 + kbase + ((n & 2) << 4) + ((n & 1) << 2));
            #pragma unroll
            for (int j = 0; j < 4; ++j) {
                const int tt = ((n & 1) << 2) + j;       // byte index in u64 half
                int mk;
                if (mbyte) mk = (int)(((n & 2) ? m1 : m0) >> (8 * tt)) & 0xff;
                else       mk = (j == 0) ? mi.x : (j == 1) ? mi.y : (j == 2) ? mi.z : mi.w;
                const float pv = mk ? 0.f : exp2f(c[j]);
                rsum += pv;
                if (n & 2) pa1[tt] = f2bfs(pv); else pa0[tt] = f2bfs(pv);
            }
        }
        __builtin_amdgcn_s_setprio(1);
        #pragma unroll
        for (int g = 0; g < 4; ++g) {
            const int d = g * 16 + lr;
            bf16x8 vf0 = *(const bf16x8*)&Vt[buf][d * KT1 + (((ch * 8 + lg)     ^ swzV(d)) << 3)];
            oacc[g] = __builtin_amdgcn_mfma_f32_16x16x32_bf16(pa0, vf0, oacc[g], 0, 0, 0);
            bf16x8 vf1 = *(const bf16x8*)&Vt[buf][d * KT1 + (((ch * 8 + 4 + lg) ^ swzV(d)) << 3)];
            oacc[g] = __builtin_amdgcn_mfma_f32_16x16x32_bf16(pa1, vf1, oacc[g], 0, 0, 0);
        }
        __builtin_amdgcn_s_setprio(0);
    };

    issS(0); comS(0);
    wg_barrier();
    #pragma unroll 1
    for (int kt = 0; kt < NT1; kt += 2) {
        {
            const uint64_t m0 = mS0, m1 = mS1;
            if (kt + 1 < NT1) issS(kt + 1);
            body(0, m0, m1, kt);
            if (kt + 1 < NT1) comS(1);
            wg_barrier();
        }
        {
            const uint64_t m0 = mS0, m1 = mS1;
            if (kt + 2 < NT1) issS(kt + 2);
            body(1, m0, m1, kt + 1);
            if (kt + 2 < NT1) comS(0);
            wg_barrier();
        }
    }

    // reduce rsum over lg within wave, then over ch via LDS
    rsum += __shfl_xor(rsum, 16, 64);
    rsum += __shfl_xor(rsum, 32, 64);
    if (lg == 0) Rs[ch * 64 + 16 * rg + lr] = rsum;
    __syncthreads();
    const float rinv = 1.0f / (Rs[16 * rg + lr] + Rs[64 + 16 * rg + lr]);
    if (ch == 0 && lg == 0) rinvw[b * LL + qrow] = rinv;

    // combine ch-halves of O via LDS (reuse retired Kt region), scale, write
    float* OutL = (float*)Kt;
    if (ch == 1) {
        #pragma unroll
        for (int g = 0; g < 4; ++g)
            #pragma unroll
            for (int j = 0; j < 4; ++j)
                OutL[rg * 1088 + (lg * 4 + j) * 68 + g * 16 + lr] = oacc[g][j];
    }
    __syncthreads();
    if (ch == 0) {
        #pragma unroll
        for (int j = 0; j < 4; ++j) {
            const int ql = 16 * rg + lg * 4 + j;
            const float ri = 1.0f / (Rs[ql] + Rs[64 + ql]);
            const size_t orow = (size_t)(b * LL + q0 + ql) * DD;
            #pragma unroll
            for (int g = 0; g < 4; ++g)
                outp[orow + g * 16 + lr] = (oacc[g][j] + OutL[rg * 1088 + (lg * 4 + j) * 68 + g * 16 + lr]) * ri;
        }
    }
}

// ===================== K2: attn writer =====================
// Recompute QK (identical fragments -> identical scores), read mask + rinv,
// stream normalized attn. No V/oacc state -> small VGPR -> 4 blocks/CU.
__global__ __launch_bounds__(512, 8) void attn_write_kernel(
    const float* __restrict__ qg, const float* __restrict__ kg,
    const void* __restrict__ maskv, const uint32_t* __restrict__ flagp,
    const float* __restrict__ rinvw, float* __restrict__ attn)
{
    __shared__ alignas(16) ushort Kt[2][KT1 * 64];   // 32 KB

    const int tid = (int)threadIdx.x;
    const int w   = tid >> 6, l = tid & 63;
    const int lr  = l & 15, lg = l >> 4;
    const int rg  = w & 3, ch = w >> 2;
    const int id  = (int)blockIdx.x;
    const int b   = id & 7;
    const int q0  = (id >> 3) * 64;
    const bool mbyte = (*flagp != 0);

    const float* kb = kg + (size_t)b * LL * DD;
    const int qrow = q0 + 16 * rg + lr;
    const uint8_t* mrow8  = (const uint8_t*)maskv + (size_t)b * LL * LL + (size_t)qrow * LL + ch * 64 + lg * 8;
    const int*     mrow32 = (const int*)maskv     + (size_t)b * LL * LL + (size_t)qrow * LL + ch * 64 + lg * 8;
    float* arow = attn + (size_t)b * LL * LL + (size_t)qrow * LL + ch * 64 + lg * 8;
    const float rinv = rinvw[b * LL + qrow];

    bf16x8 qf0, qf1;
    {
        const float* qp = qg + (size_t)(b * LL + qrow) * DD + lg * 8;
        qf0 = pack8v(*(const f32x4*)(qp)      * QSCALE, *(const f32x4*)(qp + 4)  * QSCALE);
        qf1 = pack8v(*(const f32x4*)(qp + 32) * QSCALE, *(const f32x4*)(qp + 36) * QSCALE);
    }

    const int krow0 = tid >> 3, kc8 = tid & 7;
    f32x4 kS[4]; uint64_t mS0 = 0, mS1 = 0;
    auto issS = [&](int kt) {
        const int kbase = kt * KT1;
        const float* p = kb + (size_t)(kbase + krow0) * DD + kc8 * 8;
        kS[0] = *(const f32x4*)p;            kS[1] = *(const f32x4*)(p + 4);
        const float* p2 = p + (size_t)64 * DD;
        kS[2] = *(const f32x4*)p2;           kS[3] = *(const f32x4*)(p2 + 4);
        if (mbyte) {
            mS0 = *(const uint64_t*)(mrow8 + kbase);
            mS1 = *(const uint64_t*)(mrow8 + kbase + 32);
        }
    };
    auto comS = [&](int buf) {
        *(bf16x8*)&Kt[buf][krow0 * 64 + ((kc8 ^ swzK(krow0)) << 3)] = pack8v(kS[0], kS[1]);
        const int r1 = krow0 + 64;
        *(bf16x8*)&Kt[buf][r1 * 64 + ((kc8 ^ swzK(r1)) << 3)] = pack8v(kS[2], kS[3]);
    };

    auto body = [&](int buf, uint64_t m0, uint64_t m1, int kt) {
        const int kbase = kt * KT1;
        #pragma unroll
        for (int n = 0; n < 4; ++n) {
            const int krow = ch * 64 + ((n & 2) << 4) + ((lr >> 2) << 3) + ((n & 1) << 2) + (lr & 3);
            bf16x8 k0 = *(const bf16x8*)&Kt[buf][krow * 64 + ((lg       ^ swzK(krow)) << 3)];
            bf16x8 k1 = *(const bf16x8*)&Kt[buf][krow * 64 + (((4 + lg) ^ swzK(krow)) << 3)];
            f32x4 c = {0.f, 0.f, 0.f, 0.f};
            c = __builtin_amdgcn_mfma_f32_16x16x32_bf16(k0, qf0, c, 0, 0, 0);
            c = __builtin_amdgcn_mfma_f32_16x16x32_bf16(k1, qf1, c, 0, 0, 0);
            int4 mi = {0, 0, 0, 0};
            if (!mbyte) mi = *(const int4*)(mrow32 + kbase + ((n & 2) << 4) + ((n & 1) << 2));
            f32x4 pv;
            #pragma unroll
            for (int j = 0; j < 4; ++j) {
                const int tt = ((n & 1) << 2) + j;
                int mk;
                if (mbyte) mk = (int)(((n & 2) ? m1 : m0) >> (8 * tt)) & 0xff;
                else       mk = (j == 0) ? mi.x : (j == 1) ? mi.y : (j == 2) ? mi.z : mi.w;
                pv[j] = mk ? 0.f : exp2f(c[j]) * rinv;
            }
            *(f32x4*)(arow + kbase + ((n & 2) << 4) + ((n & 1) << 2)) = pv;
        }
    };

    issS(0); comS(0);
    wg_barrier();
    #pragma unroll 1
    for (int kt = 0; kt < NT1; kt += 2) {
        {
            const uint64_t m0 = mS0, m1 = mS1;
            if (kt + 1 < NT1) issS(kt + 1);
            body(0, m0, m1, kt);
            if (kt + 1 < NT1) comS(1);
            wg_barrier();
        }
        {
            const uint64_t m0 = mS0, m1 = mS1;
            if (kt + 2 < NT1) issS(kt + 2);
            body(1, m0, m1, kt + 1);
            if (kt + 2 < NT1) comS(0);
            wg_barrier();
        }
    }
}

extern "C" void kernel_launch(void* const* d_in, const int* in_sizes, int n_in,
                              void* d_out, int out_size, void* d_ws, size_t ws_size,
                              hipStream_t stream) {
    const float* q = (const float*)d_in[0];
    const float* k = (const float*)d_in[1];
    const float* v = (const float*)d_in[2];
    const void* mask = d_in[3];
    float* attn = (float*)d_out;
    float* outp = attn + (size_t)BB * LL * LL;
    uint32_t* flagp = (uint32_t*)d_ws;
    float* rinvw = (float*)((char*)d_ws + 256);   // BB*LL floats = 128 KB

    detect_mask_kernel<<<1, 256, 0, stream>>>((const uint32_t*)mask, flagp);
    flash_kernel<<<dim3((LL / 64) * BB), 512, 0, stream>>>(q, k, v, mask, flagp, outp, rinvw);
    attn_write_kernel<<<dim3((LL / 64) * BB), 512, 0, stream>>>(q, k, mask, flagp, rinvw, attn);
}

// Round 13
// 427.831 us; speedup vs baseline: 1.4227x; 1.4227x over previous
//
#include <hip/hip_runtime.h>
#include <hip/hip_bf16.h>
#include <stdint.h>

#define BB 8
#define LL 4096
#define DD 64
#define KT 64
#define NT (LL / KT)         // 64 tiles

typedef short bf16x8 __attribute__((ext_vector_type(8)));
typedef short bf16x4 __attribute__((ext_vector_type(4)));
typedef float f32x4 __attribute__((ext_vector_type(4)));

// (1/8) * log2(e): folds softmax scale and exp->exp2.
#define QSCALE 0.1803368801111204f
#define PP 68      // f32 per Pout row (272 B: 16B-aligned, 17-bank stride)
#define MP 72      // bytes per Mt row (8-aligned)

__device__ inline short f2bfs(float x) {
    __hip_bfloat16 h = __float2bfloat16(x);
    return __builtin_bit_cast(short, h);
}

__device__ inline int swzK(int r) { return (r & 3) | (((r >> 3) & 1) << 2); }
__device__ inline int swzV(int r) { return (r & 7) ^ ((r >> 3) & 7); }

// Raw barrier: flush own LDS ops, leave global loads in flight.
__device__ inline void wg_barrier() {
    asm volatile("s_waitcnt lgkmcnt(0)" ::: "memory");
    __builtin_amdgcn_s_barrier();
    __builtin_amdgcn_sched_barrier(0);
}

__global__ void detect_mask_kernel(const uint32_t* __restrict__ w, uint32_t* __restrict__ flag) {
    __shared__ int nonbin;
    if (threadIdx.x == 0) nonbin = 0;
    __syncthreads();
    int bad = 0;
    for (int i = threadIdx.x; i < 4096; i += 256) bad |= (w[i] > 1u) ? 1 : 0;
    if (bad) atomicOr(&nonbin, 1);
    __syncthreads();
    if (threadIdx.x == 0) *flag = (uint32_t)(nonbin != 0);
}

// Block = 64 q-rows of one batch, 512 threads / 8 waves (rg=w&3 q-group, ch=w>>2
// 32-k half). All global streams are full-line-per-instruction: K/V loads 4 rows
// x 256B contig, mask staged to LDS as 8 full lines/instr/wave, attn written via
// a padded f32 LDS tile + cooperative 128B-per-row-per-instr store. Permuted-K
// QK keeps P in registers for pass-1 PV.
__global__ __launch_bounds__(512, 4) void fused_attn_kernel(
    const float* __restrict__ qg, const float* __restrict__ kg,
    const float* __restrict__ vg, const void* __restrict__ maskv,
    const uint32_t* __restrict__ flagp,
    float* __restrict__ attn, float* __restrict__ outp)
{
    __shared__ alignas(16) ushort Kt[2][KT * 64];    // bf16 K [krow][d], XOR-chunk swizzled (16 KB)
    __shared__ alignas(16) ushort Vt[2][64 * KT];    // bf16 V^T [d][k], swizzled (16 KB)
    __shared__ alignas(16) float  Pout[64 * PP];     // f32 P tile / O-exchange (17.4 KB)
    __shared__ alignas(16) uint8_t Mt[2][64 * MP];   // mask tile (9.2 KB)
    __shared__ float Rs[128];

    const int tid = (int)threadIdx.x;
    const int w   = tid >> 6, l = tid & 63;
    const int lr  = l & 15, lg = l >> 4;
    const int rg  = w & 3, ch = w >> 2;
    const int id  = (int)blockIdx.x;     // id = qt*8 + b
    const int b   = id & 7;
    const int q0  = (id >> 3) * 64;
    const bool mbyte = (*flagp != 0);

    const float* kb = kg + (size_t)b * LL * DD;
    const float* vb = vg + (size_t)b * LL * DD;
    const uint8_t* mb8 = (const uint8_t*)maskv + (size_t)b * LL * LL;
    float* attnb = attn + (size_t)b * LL * LL;
    const int qrow = q0 + 16 * rg + lr;
    const int* mrow32 = (const int*)maskv + (size_t)b * LL * LL + (size_t)qrow * LL + ch * 32 + lg * 8;

    bf16x8 qf0, qf1;
    {
        const float* qp = qg + (size_t)(b * LL + qrow) * DD + lg * 8;
        f32x4 a0 = *(const f32x4*)(qp)      * QSCALE, a1 = *(const f32x4*)(qp + 4)  * QSCALE;
        f32x4 a2 = *(const f32x4*)(qp + 32) * QSCALE, a3 = *(const f32x4*)(qp + 36) * QSCALE;
        #pragma unroll
        for (int e = 0; e < 4; ++e) { qf0[e] = f2bfs(a0[e]); qf0[4 + e] = f2bfs(a1[e]); }
        #pragma unroll
        for (int e = 0; e < 4; ++e) { qf1[e] = f2bfs(a2[e]); qf1[4 + e] = f2bfs(a3[e]); }
    }

    // ---------- staging (all loads full-line coalesced) ----------
    const int sr = tid >> 4, sc = tid & 15;     // K/V: 4 rows x 256B per instr
    const int mr = tid >> 3, mc = tid & 7;      // mask: 8 full lines per instr per wave
    f32x4 kS0, kS1, vS0, vS1;
    uint64_t mS = 0;

    auto issK = [&](int kt) {
        const float* p = kb + (size_t)(kt * KT + sr) * DD + sc * 4;
        kS0 = *(const f32x4*)p;
        kS1 = *(const f32x4*)(p + 32 * DD);
    };
    auto issV = [&](int kt) {
        const float* p = vb + (size_t)(kt * KT + sr) * DD + sc * 4;
        vS0 = *(const f32x4*)p;
        vS1 = *(const f32x4*)(p + 32 * DD);
    };
    auto issM = [&](int kt) {
        if (mbyte) mS = *(const uint64_t*)(mb8 + (size_t)(q0 + mr) * LL + kt * KT + mc * 8);
    };
    auto comK = [&](int buf) {
        bf16x4 a, c;
        #pragma unroll
        for (int e = 0; e < 4; ++e) { a[e] = f2bfs(kS0[e]); c[e] = f2bfs(kS1[e]); }
        *(bf16x4*)&Kt[buf][sr * 64 + (((sc >> 1) ^ swzK(sr)) << 3) + (sc & 1) * 4] = a;
        const int r1 = sr + 32;
        *(bf16x4*)&Kt[buf][r1 * 64 + (((sc >> 1) ^ swzK(r1)) << 3) + (sc & 1) * 4] = c;
    };
    auto comV = [&](int buf) {
        #pragma unroll
        for (int e = 0; e < 4; ++e) {
            const int d = sc * 4 + e;
            Vt[buf][d * 64 + (((sr >> 3) ^ swzV(d)) << 3) + (sr & 7)]        = (ushort)f2bfs(vS0[e]);
            Vt[buf][d * 64 + ((((sr + 32) >> 3) ^ swzV(d)) << 3) + (sr & 7)] = (ushort)f2bfs(vS1[e]);
        }
    };
    auto comM = [&](int buf) {
        if (mbyte) *(uint64_t*)&Mt[buf][mr * MP + mc * 8] = mS;
    };

    // ================= pass 1: rowsums + unnormalized PV (P in regs) =================
    float rsum = 0.f;
    f32x4 oacc[4];
    #pragma unroll
    for (int g = 0; g < 4; ++g) { f32x4 z = {0.f, 0.f, 0.f, 0.f}; oacc[g] = z; }

    auto body1 = [&](int cur, int kt) {
        uint64_t mu = 0;
        int4 mi0 = {0,0,0,0}, mi1 = {0,0,0,0};
        if (mbyte) mu = *(const uint64_t*)&Mt[cur][(16 * rg + lr) * MP + ch * 32 + lg * 8];
        else { mi0 = *(const int4*)(mrow32 + kt * KT); mi1 = *(const int4*)(mrow32 + kt * KT + 4); }
        float p8[8];
        #pragma unroll
        for (int n = 0; n < 2; ++n) {
            const int krow = ch * 32 + ((lr >> 2) << 3) + (n << 2) + (lr & 3);
            bf16x8 k0 = *(const bf16x8*)&Kt[cur][krow * 64 + ((lg       ^ swzK(krow)) << 3)];
            bf16x8 k1 = *(const bf16x8*)&Kt[cur][krow * 64 + (((4 + lg) ^ swzK(krow)) << 3)];
            f32x4 c = {0.f, 0.f, 0.f, 0.f};
            c = __builtin_amdgcn_mfma_f32_16x16x32_bf16(k0, qf0, c, 0, 0, 0);
            c = __builtin_amdgcn_mfma_f32_16x16x32_bf16(k1, qf1, c, 0, 0, 0);
            #pragma unroll
            for (int j = 0; j < 4; ++j) {
                const int t = n * 4 + j;
                int mk;
                if (mbyte) mk = (int)((mu >> (8 * t)) & 0xffu);
                else {
                    const int4 mi = n ? mi1 : mi0;
                    mk = (j == 0) ? mi.x : (j == 1) ? mi.y : (j == 2) ? mi.z : mi.w;
                }
                const float pv = mk ? 0.f : exp2f(c[j]);
                rsum += pv;
                p8[t] = pv;
            }
        }
        bf16x8 pa;
        #pragma unroll
        for (int t = 0; t < 8; ++t) pa[t] = f2bfs(p8[t]);
        __builtin_amdgcn_s_setprio(1);
        #pragma unroll
        for (int g = 0; g < 4; ++g) {
            const int d = g * 16 + lr;
            bf16x8 vf = *(const bf16x8*)&Vt[cur][d * 64 + (((ch * 4 + lg) ^ swzV(d)) << 3)];
            oacc[g] = __builtin_amdgcn_mfma_f32_16x16x32_bf16(pa, vf, oacc[g], 0, 0, 0);
        }
        __builtin_amdgcn_s_setprio(0);
    };

    issK(0); issV(0); issM(0);
    comK(0); comV(0); comM(0);
    wg_barrier();
    #pragma unroll 1
    for (int kt = 0; kt < NT; ++kt) {
        const int cur = kt & 1;
        const bool more = (kt < NT - 1);
        if (more) { issK(kt + 1); issV(kt + 1); issM(kt + 1); }
        body1(cur, kt);
        if (more) { comK(cur ^ 1); comV(cur ^ 1); comM(cur ^ 1); }
        wg_barrier();
    }

    rsum += __shfl_xor(rsum, 16, 64);
    rsum += __shfl_xor(rsum, 32, 64);
    if (lg == 0) Rs[ch * 64 + 16 * rg + lr] = rsum;
    __syncthreads();
    const float rinv = 1.0f / (Rs[16 * rg + lr] + Rs[64 + 16 * rg + lr]);

    // pass-2 prefetch issued before the (independent) O epilogue
    issK(0); issM(0);

    // epilogue: combine ch-halves of O via Pout, scale, write
    if (ch == 1) {
        #pragma unroll
        for (int g = 0; g < 4; ++g)
            #pragma unroll
            for (int j = 0; j < 4; ++j)
                Pout[(16 * rg + lg * 4 + j) * PP + g * 16 + lr] = oacc[g][j];
    }
    __syncthreads();
    if (ch == 0) {
        #pragma unroll
        for (int j = 0; j < 4; ++j) {
            const int ql = 16 * rg + lg * 4 + j;
            const float ri = 1.0f / (Rs[ql] + Rs[64 + ql]);
            const size_t orow = (size_t)(b * LL + q0 + ql) * DD;
            #pragma unroll
            for (int g = 0; g < 4; ++g)
                outp[orow + g * 16 + lr] = (oacc[g][j] + Pout[ql * PP + g * 16 + lr]) * ri;
        }
    }
    comK(0); comM(0);
    wg_barrier();

    // ================= pass 2: recompute + coalesced attn write =================
    const int rr = tid >> 3, cc = tid & 7;
    auto body2 = [&](int cur, int kt) {
        uint64_t mu = 0;
        int4 mi0 = {0,0,0,0}, mi1 = {0,0,0,0};
        if (mbyte) mu = *(const uint64_t*)&Mt[cur][(16 * rg + lr) * MP + ch * 32 + lg * 8];
        else { mi0 = *(const int4*)(mrow32 + kt * KT); mi1 = *(const int4*)(mrow32 + kt * KT + 4); }
        #pragma unroll
        for (int n = 0; n < 2; ++n) {
            const int krow = ch * 32 + ((lr >> 2) << 3) + (n << 2) + (lr & 3);
            bf16x8 k0 = *(const bf16x8*)&Kt[cur][krow * 64 + ((lg       ^ swzK(krow)) << 3)];
            bf16x8 k1 = *(const bf16x8*)&Kt[cur][krow * 64 + (((4 + lg) ^ swzK(krow)) << 3)];
            f32x4 c = {0.f, 0.f, 0.f, 0.f};
            c = __builtin_amdgcn_mfma_f32_16x16x32_bf16(k0, qf0, c, 0, 0, 0);
            c = __builtin_amdgcn_mfma_f32_16x16x32_bf16(k1, qf1, c, 0, 0, 0);
            f32x4 pv;
            #pragma unroll
            for (int j = 0; j < 4; ++j) {
                const int t = n * 4 + j;
                int mk;
                if (mbyte) mk = (int)((mu >> (8 * t)) & 0xffu);
                else {
                    const int4 mi = n ? mi1 : mi0;
                    mk = (j == 0) ? mi.x : (j == 1) ? mi.y : (j == 2) ? mi.z : mi.w;
                }
                pv[j] = mk ? 0.f : exp2f(c[j]) * rinv;
            }
            *(f32x4*)&Pout[(16 * rg + lr) * PP + ch * 32 + lg * 8 + n * 4] = pv;
        }
    };

    #pragma unroll 1
    for (int kt = 0; kt < NT; ++kt) {
        const int cur = kt & 1;
        const bool more = (kt < NT - 1);
        if (more) { issK(kt + 1); issM(kt + 1); }
        body2(cur, kt);
        wg_barrier();                       // Pout complete; Kt/Mt[cur] reads done
        {   // cooperative store: 8 lanes x 16B contiguous per row, 8 rows/wave/instr
            float4 v0 = *(const float4*)&Pout[rr * PP + cc * 4];
            float4 v1 = *(const float4*)&Pout[rr * PP + 32 + cc * 4];
            float* dst = attnb + (size_t)(q0 + rr) * LL + kt * KT + cc * 4;
            *(float4*)dst = v0;
            *(float4*)(dst + 32) = v1;
        }
        if (more) { comK(cur ^ 1); comM(cur ^ 1); }
        wg_barrier();                       // Pout free; commits visible
    }
}

extern "C" void kernel_launch(void* const* d_in, const int* in_sizes, int n_in,
                              void* d_out, int out_size, void* d_ws, size_t ws_size,
                              hipStream_t stream) {
    const float* q = (const float*)d_in[0];
    const float* k = (const float*)d_in[1];
    const float* v = (const float*)d_in[2];
    const void* mask = d_in[3];
    float* attn = (float*)d_out;
    float* outp = attn + (size_t)BB * LL * LL;
    uint32_t* flagp = (uint32_t*)d_ws;

    detect_mask_kernel<<<1, 256, 0, stream>>>((const uint32_t*)mask, flagp);
    fused_attn_kernel<<<dim3((LL / 64) * BB), 512, 0, stream>>>(q, k, v, mask, flagp, attn, outp);
}